// Round 3
// baseline (1594.243 us; speedup 1.0000x reference)
//
#include <hip/hip_runtime.h>
#include <hip/hip_bf16.h>
#include <math.h>

#define NB     4
#define CDIM   256
#define HWDIM  16384
#define LTOK   16384
#define NH     8
#define HD     32
#define FF     512
#define MTOK   (NB * LTOK)
#define NLAYER 4

typedef __bf16 bf16x8 __attribute__((ext_vector_type(8)));
typedef __bf16 bf16x4 __attribute__((ext_vector_type(4)));
typedef float  floatx4 __attribute__((ext_vector_type(4)));

// async 16-B global->LDS copy; LDS dest = wave-uniform base + lane*16
#define GLD16(gp, lp)                                                        \
    __builtin_amdgcn_global_load_lds(                                        \
        (const __attribute__((address_space(1))) void*)(gp),                 \
        (__attribute__((address_space(3))) void*)(lp), 16, 0, 0)

// ---------------------------------------------------------------------------
// fp32 -> bf16 convert (weights, once)
// ---------------------------------------------------------------------------
__global__ __launch_bounds__(256)
void f2b_kernel(const float* __restrict__ in, __bf16* __restrict__ out)
{
    int i = (blockIdx.x * 256 + threadIdx.x) * 4;
    float4 f = *(const float4*)&in[i];
    bf16x4 h;
    h[0] = (__bf16)f.x; h[1] = (__bf16)f.y; h[2] = (__bf16)f.z; h[3] = (__bf16)f.w;
    *(bf16x4*)&out[i] = h;
}

// ---------------------------------------------------------------------------
// patch embed: ref fp32 [N,C,HW] -> X bf16 [N,HW,C]
// ---------------------------------------------------------------------------
__global__ __launch_bounds__(256)
void patch_embed(const float* __restrict__ in, __bf16* __restrict__ out)
{
    __shared__ float tile[32][33];
    const int n = blockIdx.z;
    const int hw0 = blockIdx.x * 32, c0 = blockIdx.y * 32;
    const int tx = threadIdx.x, ty = threadIdx.y;
#pragma unroll
    for (int i = 0; i < 32; i += 8)
        tile[ty + i][tx] = in[(long long)n * CDIM * HWDIM + (long long)(c0 + ty + i) * HWDIM + hw0 + tx];
    __syncthreads();
#pragma unroll
    for (int i = 0; i < 32; i += 8)
        out[(long long)(n * HWDIM + hw0 + ty + i) * CDIM + c0 + tx] = (__bf16)tile[tx][ty + i];
}

// ---------------------------------------------------------------------------
// Wide GEMM core: 128 (tokens) x 256 (full output width) tile, BK=64.
// 4 waves: wm=(wave&1)*64, wn=(wave>>1)*128. Frags 4(mt) x 8(nt).
// Operands swapped in MFMA so D frag is row-major per thread
// (row = ...+l15, cols = ...+quad*4+r) -> packed bf16x4 stores [R3-verified].
// ---------------------------------------------------------------------------
#define WIDE_PROLOGUE()                                                      \
    const int tid  = threadIdx.x;                                            \
    const int lane = tid & 63;                                               \
    const int wave = tid >> 6;                                               \
    const int m0   = blockIdx.x * 128;                                       \
    const int l15  = lane & 15;                                              \
    const int quad = lane >> 4;                                              \
    const int wm   = (wave & 1) * 64;                                        \
    const int wn   = (wave >> 1) * 128;                                      \
    floatx4 acc[4][8];                                                       \
    _Pragma("unroll")                                                        \
    for (int i = 0; i < 4; ++i)                                              \
        _Pragma("unroll")                                                    \
        for (int j = 0; j < 8; ++j)                                          \
            acc[i][j] = (floatx4){0.f, 0.f, 0.f, 0.f};

#define WIDE_STAGE(Aq, Bq, KD)                                               \
    __syncthreads();                                                         \
    _Pragma("unroll")                                                        \
    for (int i = 0; i < 4; ++i) {                                            \
        int s = wave * 256 + i * 64 + lane;                                  \
        int row = s >> 3, kq = s & 7;                                        \
        GLD16(&(Aq)[(long long)(m0 + row) * (KD) + k0 + kq * 8],             \
              &Asl[(wave * 256 + i * 64) * 8]);                              \
    }                                                                        \
    _Pragma("unroll")                                                        \
    for (int i = 0; i < 8; ++i) {                                            \
        int s = wave * 512 + i * 64 + lane;                                  \
        int row = s >> 3, kq = s & 7;                                        \
        GLD16(&(Bq)[(long long)row * (KD) + k0 + kq * 8],                    \
              &Bsl[(wave * 512 + i * 64) * 8]);                              \
    }                                                                        \
    __syncthreads();

#define WIDE_MFMA()                                                          \
    _Pragma("unroll")                                                        \
    for (int ko = 0; ko < 2; ++ko) {                                         \
        bf16x8 af[4], bfr[8];                                                \
        _Pragma("unroll")                                                    \
        for (int mt = 0; mt < 4; ++mt)                                       \
            af[mt] = *(const bf16x8*)&Asl[(wm + mt * 16 + l15) * 64 + ko * 32 + quad * 8]; \
        _Pragma("unroll")                                                    \
        for (int nt = 0; nt < 8; ++nt)                                       \
            bfr[nt] = *(const bf16x8*)&Bsl[(wn + nt * 16 + l15) * 64 + ko * 32 + quad * 8]; \
        _Pragma("unroll")                                                    \
        for (int mt = 0; mt < 4; ++mt)                                       \
            _Pragma("unroll")                                                \
            for (int nt = 0; nt < 8; ++nt)                                   \
                acc[mt][nt] = __builtin_amdgcn_mfma_f32_16x16x32_bf16(       \
                    bfr[nt], af[mt], acc[mt][nt], 0, 0, 0);                  \
    }

// ---------------------------------------------------------------------------
// Fused QKV + partial-KV kernel (unchanged from R2, harness-verified).
// ---------------------------------------------------------------------------
__device__ __forceinline__ int t_idx(int c, int s)
{
    return c * 64 + (s ^ ((c & 7) << 3));
}

__global__ __launch_bounds__(256, 2)
void qkv_kv(const __bf16* __restrict__ X,
            const __bf16* __restrict__ Wq, const __bf16* __restrict__ Wk,
            const __bf16* __restrict__ Wv,
            const float* __restrict__ bq, const float* __restrict__ bk,
            const float* __restrict__ bv,
            __bf16* __restrict__ Qo, float* __restrict__ pKV,
            float* __restrict__ pKS)
{
    __shared__ __bf16 Asl[64 * 256];   // X tile [64][256]; later V^T (swizzled [256][64])
    __shared__ __bf16 Bsl[256 * 64];   // W chunk [256][64]; later K^T (swizzled [256][64])
    const int tid  = threadIdx.x;
    const int lane = tid & 63;
    const int wave = tid >> 6;
    const int m0   = blockIdx.x * 64;
    const int l15  = lane & 15;
    const int quad = lane >> 4;
    const int wm   = (wave & 1) * 32;     // token sub-tile
    const int wn   = (wave >> 1) * 128;   // out-col sub-tile

    // stage full X tile once: 64 rows x 256 cols bf16 = 32 KB
#pragma unroll
    for (int i = 0; i < 8; ++i) {
        int s = i * 256 + wave * 64 + lane;
        int row = s >> 5, kq = s & 31;
        GLD16(&X[(long long)(m0 + row) * CDIM + kq * 8], &Asl[(i * 256 + wave * 64) * 8]);
    }

    floatx4 acc[2][8];
    bf16x4  kbf[2][8];

#pragma unroll
    for (int sel = 0; sel < 3; ++sel) {
        const __bf16* B = (sel == 0) ? Wq : (sel == 1) ? Wk : Wv;
#pragma unroll
        for (int i = 0; i < 2; ++i)
#pragma unroll
            for (int j = 0; j < 8; ++j)
                acc[i][j] = (floatx4){0.f, 0.f, 0.f, 0.f};

        for (int k0 = 0; k0 < CDIM; k0 += 64) {
            __syncthreads();
#pragma unroll
            for (int i = 0; i < 8; ++i) {
                int s = wave * 512 + i * 64 + lane;
                int row = s >> 3, kq = s & 7;
                GLD16(&B[(long long)row * CDIM + k0 + kq * 8], &Bsl[(wave * 512 + i * 64) * 8]);
            }
            __syncthreads();
#pragma unroll
            for (int ko = 0; ko < 2; ++ko) {
                bf16x8 af[2], bfr[8];
#pragma unroll
                for (int mt = 0; mt < 2; ++mt)
                    af[mt] = *(const bf16x8*)&Asl[(wm + mt * 16 + l15) * 256 + k0 + ko * 32 + quad * 8];
#pragma unroll
                for (int nt = 0; nt < 8; ++nt)
                    bfr[nt] = *(const bf16x8*)&Bsl[(wn + nt * 16 + l15) * 64 + ko * 32 + quad * 8];
#pragma unroll
                for (int mt = 0; mt < 2; ++mt)
#pragma unroll
                    for (int nt = 0; nt < 8; ++nt)
                        acc[mt][nt] = __builtin_amdgcn_mfma_f32_16x16x32_bf16(
                            bfr[nt], af[mt], acc[mt][nt], 0, 0, 0);
            }
        }

        if (sel == 0) {
#pragma unroll
            for (int mt = 0; mt < 2; ++mt) {
                int row = m0 + wm + mt * 16 + l15;
#pragma unroll
                for (int nt = 0; nt < 8; ++nt) {
                    int col0 = wn + nt * 16 + quad * 4;
                    float4 bb = *(const float4*)&bq[col0];
                    bf16x4 o;
#pragma unroll
                    for (int r = 0; r < 4; ++r) {
                        float v = acc[mt][nt][r] + ((r == 0) ? bb.x : (r == 1) ? bb.y : (r == 2) ? bb.z : bb.w);
                        v = v > 0.f ? v + 1.f : __expf(v);
                        o[r] = (__bf16)v;
                    }
                    *(bf16x4*)&Qo[(long long)row * CDIM + col0] = o;
                }
            }
        } else if (sel == 1) {
#pragma unroll
            for (int mt = 0; mt < 2; ++mt)
#pragma unroll
                for (int nt = 0; nt < 8; ++nt) {
                    int col0 = wn + nt * 16 + quad * 4;
                    float4 bb = *(const float4*)&bk[col0];
#pragma unroll
                    for (int r = 0; r < 4; ++r) {
                        float v = acc[mt][nt][r] + ((r == 0) ? bb.x : (r == 1) ? bb.y : (r == 2) ? bb.z : bb.w);
                        v = v > 0.f ? v + 1.f : __expf(v);
                        kbf[mt][nt][r] = (__bf16)v;
                    }
                }
        }
    }

    // ---- write K^T / V^T (swizzled) over the dead A/B LDS regions ----
    __syncthreads();
    {
        __bf16* KT = Bsl;
        __bf16* VT = Asl;
#pragma unroll
        for (int nt = 0; nt < 8; ++nt) {
            int col0 = wn + nt * 16 + quad * 4;
            float4 bb = *(const float4*)&bv[col0];
#pragma unroll
            for (int mt = 0; mt < 2; ++mt) {
                int row_t = wm + mt * 16 + l15;
#pragma unroll
                for (int r = 0; r < 4; ++r) {
                    KT[t_idx(col0 + r, row_t)] = kbf[mt][nt][r];
                    float vv = acc[mt][nt][r] + ((r == 0) ? bb.x : (r == 1) ? bb.y : (r == 2) ? bb.z : bb.w);
                    VT[t_idx(col0 + r, row_t)] = (__bf16)vv;
                }
            }
        }
    }
    __syncthreads();

    // ---- KS partial: column sums of feature-mapped K (staggered reads) ----
    {
        const __bf16* KT = Bsl;
        float s = 0.f;
#pragma unroll 8
        for (int i = 0; i < 64; ++i) {
            int ss = (i + tid) & 63;
            s += (float)KT[t_idx(tid, ss)];
        }
        pKS[(long long)blockIdx.x * 256 + tid] = s;
    }

    // ---- KV partial via MFMA: D[m][d] = sum_s V^T[m][s] * K[s][d] ----
    {
        const __bf16* KT = Bsl;
        const __bf16* VT = Asl;
        float* outKV = pKV + (long long)blockIdx.x * 8192;
#pragma unroll
        for (int hh = 0; hh < 2; ++hh) {
            int h = wave * 2 + hh;
            floatx4 kv[2][2];
#pragma unroll
            for (int mi = 0; mi < 2; ++mi)
#pragma unroll
                for (int di = 0; di < 2; ++di)
                    kv[mi][di] = (floatx4){0.f, 0.f, 0.f, 0.f};
#pragma unroll
            for (int ks = 0; ks < 2; ++ks) {
                bf16x8 a[2], b[2];
#pragma unroll
                for (int mi = 0; mi < 2; ++mi)
                    a[mi] = *(const bf16x8*)&VT[t_idx(h * 32 + mi * 16 + l15, ks * 32 + quad * 8)];
#pragma unroll
                for (int di = 0; di < 2; ++di)
                    b[di] = *(const bf16x8*)&KT[t_idx(h * 32 + di * 16 + l15, ks * 32 + quad * 8)];
#pragma unroll
                for (int mi = 0; mi < 2; ++mi)
#pragma unroll
                    for (int di = 0; di < 2; ++di)
                        kv[mi][di] = __builtin_amdgcn_mfma_f32_16x16x32_bf16(
                            a[mi], b[di], kv[mi][di], 0, 0, 0);
            }
#pragma unroll
            for (int mi = 0; mi < 2; ++mi)
#pragma unroll
                for (int di = 0; di < 2; ++di)
#pragma unroll
                    for (int r = 0; r < 4; ++r)
                        outKV[(long long)h * 1024 + (mi * 16 + quad * 4 + r) * 32 + di * 16 + l15]
                            = kv[mi][di][r];
        }
    }
}

// ---------------------------------------------------------------------------
// Reduce per-block partial KV/KS -> KVb/KSb.
// ---------------------------------------------------------------------------
__global__ __launch_bounds__(256)
void kv_reduce(const float* __restrict__ pKV, const float* __restrict__ pKS,
               float* __restrict__ KV, float* __restrict__ KS)
{
    __shared__ float red[256];
    const int bid = blockIdx.x, tid = threadIdx.x;
    if (bid < 256) {
        int o = bid * 128 + (tid & 127);      // 0..32767 : n*8192 + h*1024 + m*32 + d
        int half = tid >> 7;
        int n = o >> 13, r = o & 8191;
        const float* p = pKV + ((long long)n * 256 + half * 128) * 8192 + r;
        float s = 0.f;
#pragma unroll 8
        for (int b = 0; b < 128; ++b) s += p[(long long)b * 8192];
        red[tid] = s;
        __syncthreads();
        if (half == 0) KV[o] = red[tid] + red[tid + 128];
    } else {
        int n = bid - 256;
        const float* p = pKS + (long long)n * 256 * 256 + tid;
        float s = 0.f;
#pragma unroll 8
        for (int b = 0; b < 256; ++b) s += p[b * 256];
        KS[n * 256 + tid] = s;
    }
}

// ---------------------------------------------------------------------------
// GEMM + residual + LayerNorm fused:  X = LN(X + A@B^T + bias) * g + be
// ---------------------------------------------------------------------------
template <int KDIM>
__global__ __launch_bounds__(256, 2)
void gemm_ln(const __bf16* __restrict__ A, const __bf16* __restrict__ B,
             const float* __restrict__ bias, __bf16* X,
             const float* __restrict__ g, const float* __restrict__ be)
{
    __shared__ __bf16 Asl[128 * 64];
    __shared__ __bf16 Bsl[256 * 64];

    WIDE_PROLOGUE()
    for (int k0 = 0; k0 < KDIM; k0 += 64) {
        WIDE_STAGE(A, B, KDIM)
        WIDE_MFMA()
    }

    // bias + residual into fp32 acc
#pragma unroll
    for (int mt = 0; mt < 4; ++mt) {
        int row = m0 + wm + mt * 16 + l15;
#pragma unroll
        for (int nt = 0; nt < 8; ++nt) {
            int col0 = wn + nt * 16 + quad * 4;
            float4 bb = *(const float4*)&bias[col0];
            bf16x4 xr = *(const bf16x4*)&X[(long long)row * CDIM + col0];
            acc[mt][nt][0] += bb.x + (float)xr[0];
            acc[mt][nt][1] += bb.y + (float)xr[1];
            acc[mt][nt][2] += bb.z + (float)xr[2];
            acc[mt][nt][3] += bb.w + (float)xr[3];
        }
    }

    float psum[4], psq[4];
#pragma unroll
    for (int mt = 0; mt < 4; ++mt) {
        float s = 0.f, q = 0.f;
#pragma unroll
        for (int nt = 0; nt < 8; ++nt)
#pragma unroll
            for (int r = 0; r < 4; ++r) {
                float v = acc[mt][nt][r];
                s += v; q += v * v;
            }
        s += __shfl_xor(s, 16, 64); s += __shfl_xor(s, 32, 64);
        q += __shfl_xor(q, 16, 64); q += __shfl_xor(q, 32, 64);
        psum[mt] = s; psq[mt] = q;
    }

    float* red = (float*)Asl;           // red[row_local*4 + half*2 + {0,1}]
    const int half = wave >> 1;
    __syncthreads();
    if (quad == 0) {
#pragma unroll
        for (int mt = 0; mt < 4; ++mt) {
            int rl = wm + mt * 16 + l15;
            red[rl * 4 + half * 2 + 0] = psum[mt];
            red[rl * 4 + half * 2 + 1] = psq[mt];
        }
    }
    __syncthreads();

#pragma unroll
    for (int mt = 0; mt < 4; ++mt) {
        int rl  = wm + mt * 16 + l15;
        float tot = red[rl * 4 + 0] + red[rl * 4 + 2];
        float tsq = red[rl * 4 + 1] + red[rl * 4 + 3];
        float mean = tot * (1.f / 256.f);
        float var  = tsq * (1.f / 256.f) - mean * mean;
        float rstd = rsqrtf(var + 1e-5f);
        int row = m0 + rl;
#pragma unroll
        for (int nt = 0; nt < 8; ++nt) {
            int col0 = wn + nt * 16 + quad * 4;
            float4 gg = *(const float4*)&g[col0];
            float4 ee = *(const float4*)&be[col0];
            bf16x4 o;
            o[0] = (__bf16)((acc[mt][nt][0] - mean) * rstd * gg.x + ee.x);
            o[1] = (__bf16)((acc[mt][nt][1] - mean) * rstd * gg.y + ee.y);
            o[2] = (__bf16)((acc[mt][nt][2] - mean) * rstd * gg.z + ee.z);
            o[3] = (__bf16)((acc[mt][nt][3] - mean) * rstd * gg.w + ee.w);
            *(bf16x4*)&X[(long long)row * CDIM + col0] = o;
        }
    }
}

// ---------------------------------------------------------------------------
// Fully fused FFN:  X = LN(X + relu(X@W1^T + c1)@W2^T + c2) * g + be
// + writes the layer's fp32 [C, L] output (replaces out_transpose).
// 64-token block, 512 threads (8 waves: wr=(wave&3)*16 tokens, wc=(wave>>2)*128 cols).
// LDS: Asl = X tile 32 KB (resident; residual source)
//      Bsl = W chunk 32 KB (staging; later LN scratch)
//      Hs  = H tile  64 KB bf16, 16B-chunk XOR-swizzled (chunk ^= row&7);
//            later reused as fp32 [256 c][64 tok] transpose buffer.
// 128 KB LDS -> 1 block/CU = 2 waves/SIMD (same occupancy as 48KB/2-block kernels).
// ---------------------------------------------------------------------------
__global__ __launch_bounds__(512, 2)
void ffn_fused(__bf16* __restrict__ X,
               const __bf16* __restrict__ W1, const float* __restrict__ c1,
               const __bf16* __restrict__ W2, const float* __restrict__ c2,
               const float* __restrict__ g,  const float* __restrict__ be,
               float* __restrict__ out)
{
    __shared__ __bf16 Asl[64 * 256];
    __shared__ __bf16 Bsl[256 * 64];
    __shared__ __bf16 Hs[64 * 512];

    const int tid  = threadIdx.x;
    const int lane = tid & 63;
    const int wave = tid >> 6;           // 0..7
    const int m0   = blockIdx.x * 64;
    const int l15  = lane & 15;
    const int quad = lane >> 4;
    const int wr   = (wave & 3) * 16;    // token sub-row base
    const int wc   = (wave >> 2) * 128;  // col half base
    const int row  = wr + l15;           // this thread's local token row
    const int rx   = row & 7;            // Hs swizzle key

    // stage X tile [64][256] bf16 (linear)
#pragma unroll
    for (int i = 0; i < 4; ++i) {
        int s = i * 512 + wave * 64 + lane;          // 16B chunk id, 0..2047
        int rr = s >> 5, c8 = s & 31;
        GLD16(&X[(long long)(m0 + rr) * CDIM + c8 * 8], &Asl[s * 8]);
    }

    floatx4 acc[8];

    // ---- GEMM1: H = relu(X@W1^T + c1), two 256-wide passes into Hs ----
#pragma unroll
    for (int p = 0; p < 2; ++p) {
#pragma unroll
        for (int j = 0; j < 8; ++j) acc[j] = (floatx4){0.f, 0.f, 0.f, 0.f};
        for (int k0 = 0; k0 < CDIM; k0 += 64) {
            __syncthreads();
#pragma unroll
            for (int i = 0; i < 4; ++i) {
                int s = i * 512 + wave * 64 + lane;   // 0..2047
                int rr = s >> 3, kq = s & 7;
                GLD16(&W1[(long long)(p * 256 + rr) * CDIM + k0 + kq * 8], &Bsl[s * 8]);
            }
            __syncthreads();
#pragma unroll
            for (int ko = 0; ko < 2; ++ko) {
                bf16x8 af = *(const bf16x8*)&Asl[row * 256 + k0 + ko * 32 + quad * 8];
                bf16x8 bfr[8];
#pragma unroll
                for (int nt = 0; nt < 8; ++nt)
                    bfr[nt] = *(const bf16x8*)&Bsl[(wc + nt * 16 + l15) * 64 + ko * 32 + quad * 8];
#pragma unroll
                for (int nt = 0; nt < 8; ++nt)
                    acc[nt] = __builtin_amdgcn_mfma_f32_16x16x32_bf16(bfr[nt], af, acc[nt], 0, 0, 0);
            }
        }
        // relu(acc + c1) -> Hs (swizzled); fenced by next stage's barrier
#pragma unroll
        for (int nt = 0; nt < 8; ++nt) {
            int hc = p * 256 + wc + nt * 16 + quad * 4;
            float4 bb = *(const float4*)&c1[hc];
            bf16x4 o;
#pragma unroll
            for (int r = 0; r < 4; ++r) {
                float v = acc[nt][r] + ((r == 0) ? bb.x : (r == 1) ? bb.y : (r == 2) ? bb.z : bb.w);
                o[r] = (__bf16)(v > 0.f ? v : 0.f);
            }
            int hc8 = hc >> 3;
            *(bf16x4*)&Hs[row * 512 + (((hc8 ^ rx) << 3) | (hc & 7))] = o;
        }
    }

    // ---- GEMM2: Y = H@W2^T, K = 512 from Hs ----
#pragma unroll
    for (int j = 0; j < 8; ++j) acc[j] = (floatx4){0.f, 0.f, 0.f, 0.f};
    for (int k0 = 0; k0 < FF; k0 += 64) {
        __syncthreads();
#pragma unroll
        for (int i = 0; i < 4; ++i) {
            int s = i * 512 + wave * 64 + lane;
            int rr = s >> 3, kq = s & 7;
            GLD16(&W2[(long long)rr * FF + k0 + kq * 8], &Bsl[s * 8]);
        }
        __syncthreads();
#pragma unroll
        for (int ko = 0; ko < 2; ++ko) {
            int k8 = (k0 >> 3) + ko * 4 + quad;        // logical 16B chunk in [0,64)
            bf16x8 af = *(const bf16x8*)&Hs[row * 512 + ((k8 ^ rx) << 3)];
            bf16x8 bfr[8];
#pragma unroll
            for (int nt = 0; nt < 8; ++nt)
                bfr[nt] = *(const bf16x8*)&Bsl[(wc + nt * 16 + l15) * 64 + ko * 32 + quad * 8];
#pragma unroll
            for (int nt = 0; nt < 8; ++nt)
                acc[nt] = __builtin_amdgcn_mfma_f32_16x16x32_bf16(bfr[nt], af, acc[nt], 0, 0, 0);
        }
    }

    // ---- bias + residual (from Asl) ----
#pragma unroll
    for (int nt = 0; nt < 8; ++nt) {
        int col0 = wc + nt * 16 + quad * 4;
        float4 bb = *(const float4*)&c2[col0];
        bf16x4 xr = *(const bf16x4*)&Asl[row * 256 + col0];
        acc[nt][0] += bb.x + (float)xr[0];
        acc[nt][1] += bb.y + (float)xr[1];
        acc[nt][2] += bb.z + (float)xr[2];
        acc[nt][3] += bb.w + (float)xr[3];
    }

    // ---- LN: per-row sums over this wave's 128-col half, quad-reduce ----
    float s = 0.f, q = 0.f;
#pragma unroll
    for (int nt = 0; nt < 8; ++nt)
#pragma unroll
        for (int r = 0; r < 4; ++r) {
            float v = acc[nt][r];
            s += v; q += v * v;
        }
    s += __shfl_xor(s, 16, 64); s += __shfl_xor(s, 32, 64);
    q += __shfl_xor(q, 16, 64); q += __shfl_xor(q, 32, 64);

    // cross-half reduction via Bsl (dead after GEMM2); fence GEMM2 reads first
    float* red = (float*)Bsl;            // red[row*4 + half*2 + {0,1}]
    const int half = wave >> 2;
    __syncthreads();
    if (quad == 0) {
        red[row * 4 + half * 2 + 0] = s;
        red[row * 4 + half * 2 + 1] = q;
    }
    __syncthreads();

    float tot  = red[row * 4 + 0] + red[row * 4 + 2];
    float tsq  = red[row * 4 + 1] + red[row * 4 + 3];
    float mean = tot * (1.f / 256.f);
    float var  = tsq * (1.f / 256.f) - mean * mean;
    float rstd = rsqrtf(var + 1e-5f);

    // ---- normalize: store X bf16 + stash fp32 into Hf (Hs reused) ----
    float* Hf = (float*)Hs;              // [256 c][64 tok]
#pragma unroll
    for (int nt = 0; nt < 8; ++nt) {
        int col0 = wc + nt * 16 + quad * 4;
        float4 gg = *(const float4*)&g[col0];
        float4 ee = *(const float4*)&be[col0];
        bf16x4 o;
#pragma unroll
        for (int r = 0; r < 4; ++r) {
            float gv = (r == 0) ? gg.x : (r == 1) ? gg.y : (r == 2) ? gg.z : gg.w;
            float ev = (r == 0) ? ee.x : (r == 1) ? ee.y : (r == 2) ? ee.z : ee.w;
            float v  = (acc[nt][r] - mean) * rstd * gv + ev;
            o[r] = (__bf16)v;
            Hf[(col0 + r) * 64 + row] = v;
        }
        *(bf16x4*)&X[(long long)(m0 + row) * CDIM + col0] = o;
    }
    __syncthreads();

    // ---- coalesced fp32 [C, L] output: thread t -> c = t>>1, 32-tok half ----
    {
        const int n  = m0 >> 14;            // token block's batch index
        const int l0 = m0 & (LTOK - 1);
        int c  = tid >> 1;
        int hh = (tid & 1) * 32;
        const float4* src = (const float4*)&Hf[c * 64 + hh];
        float4* dst = (float4*)&out[(long long)n * CDIM * LTOK + (long long)c * LTOK + l0 + hh];
#pragma unroll
        for (int i = 0; i < 8; ++i) dst[i] = src[i];
    }
}

// ---------------------------------------------------------------------------
// attn[n,l,h,m] = (Q·KV row m) / (Q·KS + eps); KV/KS rows in registers
// ---------------------------------------------------------------------------
__global__ __launch_bounds__(256)
void attn_kernel(const __bf16* __restrict__ Q, const float* __restrict__ KV,
                 const float* __restrict__ KS, __bf16* __restrict__ out)
{
    __shared__ float q_lds[16 * 256];
    const int n = blockIdx.y;
    const int tid = threadIdx.x;
    const int h = tid >> 5;
    const int m = tid & 31;

    float4 kvr[8], ksr[8];
    {
        const float4* kvp = (const float4*)&KV[(((long long)n * NH + h) * HD + m) * HD];
        const float4* ksp = (const float4*)&KS[((long long)n * NH + h) * HD];
#pragma unroll
        for (int i = 0; i < 8; ++i) { kvr[i] = kvp[i]; ksr[i] = ksp[i]; }
    }

    for (int it = 0; it < 4; ++it) {
        int l0 = blockIdx.x * 64 + it * 16;
        __syncthreads();
#pragma unroll
        for (int i = 0; i < 4; ++i) {
            int e = tid * 4 + i * 1024;
            int row = e >> 8, col = e & 255;
            bf16x4 q4 = *(const bf16x4*)&Q[(long long)(n * LTOK + l0 + row) * CDIM + col];
            float4 f;
            f.x = (float)q4[0]; f.y = (float)q4[1]; f.z = (float)q4[2]; f.w = (float)q4[3];
            *(float4*)&q_lds[e] = f;
        }
        __syncthreads();
#pragma unroll 2
        for (int t = 0; t < 16; ++t) {
            const float4* qr = (const float4*)&q_lds[t * 256 + h * 32];
            float num = 0.f, den = 0.f;
#pragma unroll
            for (int i = 0; i < 8; ++i) {
                float4 q4 = qr[i];
                num += q4.x * kvr[i].x + q4.y * kvr[i].y + q4.z * kvr[i].z + q4.w * kvr[i].w;
                den += q4.x * ksr[i].x + q4.y * ksr[i].y + q4.z * ksr[i].z + q4.w * ksr[i].w;
            }
            out[(long long)(n * LTOK + l0 + t) * CDIM + tid] = (__bf16)(num / (den + 1e-6f));
        }
    }
}

// ---------------------------------------------------------------------------
// Launch
// ---------------------------------------------------------------------------
extern "C" void kernel_launch(void* const* d_in, const int* in_sizes, int n_in,
                              void* d_out, int out_size, void* d_ws, size_t ws_size,
                              hipStream_t stream)
{
    const float* ref = (const float*)d_in[0];
    const float* Wq  = (const float*)d_in[1];  const float* bq = (const float*)d_in[2];
    const float* Wk  = (const float*)d_in[3];  const float* bk = (const float*)d_in[4];
    const float* Wv  = (const float*)d_in[5];  const float* bv = (const float*)d_in[6];
    const float* Wo  = (const float*)d_in[7];  const float* bo = (const float*)d_in[8];
    const float* g1  = (const float*)d_in[9];  const float* be1 = (const float*)d_in[10];
    const float* W1  = (const float*)d_in[11]; const float* c1 = (const float*)d_in[12];
    const float* W2  = (const float*)d_in[13]; const float* c2 = (const float*)d_in[14];
    const float* g2  = (const float*)d_in[15]; const float* be2 = (const float*)d_in[16];
    float* out = (float*)d_out;

    const size_t SZ = (size_t)MTOK * CDIM;
    __bf16* Xb = (__bf16*)d_ws;
    __bf16* Qb = Xb + SZ;
    __bf16* Kb = Qb + SZ;                    // layer loop: pKV partials, then attn out
    __bf16* Vb = Kb + SZ;                    // layer loop: pKS partials
    __bf16* Hb = Vb + SZ;                    // (now only used as spare)
    float*  KVb = (float*)(Hb + 2 * SZ);
    float*  KSb = KVb + NB * NH * HD * HD;
    __bf16* Wqb = (__bf16*)(KSb + NB * NH * HD);
    const size_t WC = (size_t)NLAYER * CDIM * CDIM;
    const size_t WF = (size_t)NLAYER * FF * CDIM;
    __bf16* Wkb = Wqb + WC;
    __bf16* Wvb = Wkb + WC;
    __bf16* Wob = Wvb + WC;
    __bf16* W1b = Wob + WC;
    __bf16* W2b = W1b + WF;

    f2b_kernel<<<WC / 1024, 256, 0, stream>>>(Wq, Wqb);
    f2b_kernel<<<WC / 1024, 256, 0, stream>>>(Wk, Wkb);
    f2b_kernel<<<WC / 1024, 256, 0, stream>>>(Wv, Wvb);
    f2b_kernel<<<WC / 1024, 256, 0, stream>>>(Wo, Wob);
    f2b_kernel<<<WF / 1024, 256, 0, stream>>>(W1, W1b);
    f2b_kernel<<<WF / 1024, 256, 0, stream>>>(W2, W2b);

    dim3 tb(32, 8);
    patch_embed<<<dim3(HWDIM / 32, CDIM / 32, NB), tb, 0, stream>>>(ref, Xb);

    for (int l = 0; l < NLAYER; ++l) {
        const __bf16* Wq_l = Wqb + (size_t)l * CDIM * CDIM;
        const __bf16* Wk_l = Wkb + (size_t)l * CDIM * CDIM;
        const __bf16* Wv_l = Wvb + (size_t)l * CDIM * CDIM;
        const __bf16* Wo_l = Wob + (size_t)l * CDIM * CDIM;
        const __bf16* W1_l = W1b + (size_t)l * FF * CDIM;
        const __bf16* W2_l = W2b + (size_t)l * CDIM * FF;
        const float* bq_l = bq + (size_t)l * CDIM;
        const float* bk_l = bk + (size_t)l * CDIM;
        const float* bv_l = bv + (size_t)l * CDIM;
        const float* bo_l = bo + (size_t)l * CDIM;
        const float* c1_l = c1 + (size_t)l * FF;
        const float* c2_l = c2 + (size_t)l * CDIM;
        const float* g1_l = g1 + (size_t)l * CDIM;
        const float* g2_l = g2 + (size_t)l * CDIM;
        const float* be1_l = be1 + (size_t)l * CDIM;
        const float* be2_l = be2 + (size_t)l * CDIM;

        // fused QKV + partial KV/KS (X read once; K,V never hit global)
        qkv_kv<<<MTOK / 64, 256, 0, stream>>>(
            Xb, Wq_l, Wk_l, Wv_l, bq_l, bk_l, bv_l,
            Qb, (float*)Kb, (float*)Vb);

        kv_reduce<<<260, 256, 0, stream>>>((const float*)Kb, (const float*)Vb, KVb, KSb);

        attn_kernel<<<dim3(LTOK / 64, NB), 256, 0, stream>>>(Qb, KVb, KSb, Kb);

        // X = LN(X + attn@Wo^T + bo)
        gemm_ln<CDIM><<<MTOK / 128, 256, 0, stream>>>(Kb, Wo_l, bo_l, Xb, g1_l, be1_l);

        // X = LN(X + relu(X@W1^T+c1)@W2^T + c2), + fp32 [C,L] layer output
        ffn_fused<<<MTOK / 64, 512, 0, stream>>>(
            Xb, W1_l, c1_l, W2_l, c2_l, g2_l, be2_l,
            out + (size_t)l * NB * CDIM * LTOK);
    }
}

// Round 4
// 1359.263 us; speedup vs baseline: 1.1729x; 1.1729x over previous
//
#include <hip/hip_runtime.h>
#include <hip/hip_bf16.h>
#include <math.h>

#define NB     4
#define CDIM   256
#define HWDIM  16384
#define LTOK   16384
#define NH     8
#define HD     32
#define FF     512
#define MTOK   (NB * LTOK)
#define NLAYER 4

typedef __bf16 bf16x8 __attribute__((ext_vector_type(8)));
typedef __bf16 bf16x4 __attribute__((ext_vector_type(4)));
typedef float  floatx4 __attribute__((ext_vector_type(4)));

// async 16-B global->LDS copy; LDS dest = wave-uniform base + lane*16
#define GLD16(gp, lp)                                                        \
    __builtin_amdgcn_global_load_lds(                                        \
        (const __attribute__((address_space(1))) void*)(gp),                 \
        (__attribute__((address_space(3))) void*)(lp), 16, 0, 0)

// ---------------------------------------------------------------------------
// fp32 -> bf16 convert (weights, once)
// ---------------------------------------------------------------------------
__global__ __launch_bounds__(256)
void f2b_kernel(const float* __restrict__ in, __bf16* __restrict__ out)
{
    int i = (blockIdx.x * 256 + threadIdx.x) * 4;
    float4 f = *(const float4*)&in[i];
    bf16x4 h;
    h[0] = (__bf16)f.x; h[1] = (__bf16)f.y; h[2] = (__bf16)f.z; h[3] = (__bf16)f.w;
    *(bf16x4*)&out[i] = h;
}

// ---------------------------------------------------------------------------
// patch embed: ref fp32 [N,C,HW] -> X bf16 [N,HW,C]
// ---------------------------------------------------------------------------
__global__ __launch_bounds__(256)
void patch_embed(const float* __restrict__ in, __bf16* __restrict__ out)
{
    __shared__ float tile[32][33];
    const int n = blockIdx.z;
    const int hw0 = blockIdx.x * 32, c0 = blockIdx.y * 32;
    const int tx = threadIdx.x, ty = threadIdx.y;
#pragma unroll
    for (int i = 0; i < 32; i += 8)
        tile[ty + i][tx] = in[(long long)n * CDIM * HWDIM + (long long)(c0 + ty + i) * HWDIM + hw0 + tx];
    __syncthreads();
#pragma unroll
    for (int i = 0; i < 32; i += 8)
        out[(long long)(n * HWDIM + hw0 + ty + i) * CDIM + c0 + tx] = (__bf16)tile[tx][ty + i];
}

// ---------------------------------------------------------------------------
// Wide GEMM core: 128 (tokens) x 256 (full output width) tile, BK=64.
// 4 waves: wm=(wave&1)*64, wn=(wave>>1)*128. Frags 4(mt) x 8(nt).
// Operands swapped in MFMA so D frag is row-major per thread
// (row = ...+l15, cols = ...+quad*4+r) -> packed bf16x4 stores [R3-verified].
// ---------------------------------------------------------------------------
#define WIDE_PROLOGUE()                                                      \
    const int tid  = threadIdx.x;                                            \
    const int lane = tid & 63;                                               \
    const int wave = tid >> 6;                                               \
    const int m0   = blockIdx.x * 128;                                       \
    const int l15  = lane & 15;                                              \
    const int quad = lane >> 4;                                              \
    const int wm   = (wave & 1) * 64;                                        \
    const int wn   = (wave >> 1) * 128;                                      \
    floatx4 acc[4][8];                                                       \
    _Pragma("unroll")                                                        \
    for (int i = 0; i < 4; ++i)                                              \
        _Pragma("unroll")                                                    \
        for (int j = 0; j < 8; ++j)                                          \
            acc[i][j] = (floatx4){0.f, 0.f, 0.f, 0.f};

#define WIDE_STAGE(Aq, Bq, KD)                                               \
    __syncthreads();                                                         \
    _Pragma("unroll")                                                        \
    for (int i = 0; i < 4; ++i) {                                            \
        int s = wave * 256 + i * 64 + lane;                                  \
        int row = s >> 3, kq = s & 7;                                        \
        GLD16(&(Aq)[(long long)(m0 + row) * (KD) + k0 + kq * 8],             \
              &Asl[(wave * 256 + i * 64) * 8]);                              \
    }                                                                        \
    _Pragma("unroll")                                                        \
    for (int i = 0; i < 8; ++i) {                                            \
        int s = wave * 512 + i * 64 + lane;                                  \
        int row = s >> 3, kq = s & 7;                                        \
        GLD16(&(Bq)[(long long)row * (KD) + k0 + kq * 8],                    \
              &Bsl[(wave * 512 + i * 64) * 8]);                              \
    }                                                                        \
    __syncthreads();

#define WIDE_MFMA()                                                          \
    _Pragma("unroll")                                                        \
    for (int ko = 0; ko < 2; ++ko) {                                         \
        bf16x8 af[4], bfr[8];                                                \
        _Pragma("unroll")                                                    \
        for (int mt = 0; mt < 4; ++mt)                                       \
            af[mt] = *(const bf16x8*)&Asl[(wm + mt * 16 + l15) * 64 + ko * 32 + quad * 8]; \
        _Pragma("unroll")                                                    \
        for (int nt = 0; nt < 8; ++nt)                                       \
            bfr[nt] = *(const bf16x8*)&Bsl[(wn + nt * 16 + l15) * 64 + ko * 32 + quad * 8]; \
        _Pragma("unroll")                                                    \
        for (int mt = 0; mt < 4; ++mt)                                       \
            _Pragma("unroll")                                                \
            for (int nt = 0; nt < 8; ++nt)                                   \
                acc[mt][nt] = __builtin_amdgcn_mfma_f32_16x16x32_bf16(       \
                    bfr[nt], af[mt], acc[mt][nt], 0, 0, 0);                  \
    }

// ---------------------------------------------------------------------------
// Fused QKV + partial-KV kernel (unchanged from R2, harness-verified).
// ---------------------------------------------------------------------------
__device__ __forceinline__ int t_idx(int c, int s)
{
    return c * 64 + (s ^ ((c & 7) << 3));
}

__global__ __launch_bounds__(256, 2)
void qkv_kv(const __bf16* __restrict__ X,
            const __bf16* __restrict__ Wq, const __bf16* __restrict__ Wk,
            const __bf16* __restrict__ Wv,
            const float* __restrict__ bq, const float* __restrict__ bk,
            const float* __restrict__ bv,
            __bf16* __restrict__ Qo, float* __restrict__ pKV,
            float* __restrict__ pKS)
{
    __shared__ __bf16 Asl[64 * 256];   // X tile [64][256]; later V^T (swizzled [256][64])
    __shared__ __bf16 Bsl[256 * 64];   // W chunk [256][64]; later K^T (swizzled [256][64])
    const int tid  = threadIdx.x;
    const int lane = tid & 63;
    const int wave = tid >> 6;
    const int m0   = blockIdx.x * 64;
    const int l15  = lane & 15;
    const int quad = lane >> 4;
    const int wm   = (wave & 1) * 32;     // token sub-tile
    const int wn   = (wave >> 1) * 128;   // out-col sub-tile

    // stage full X tile once: 64 rows x 256 cols bf16 = 32 KB
#pragma unroll
    for (int i = 0; i < 8; ++i) {
        int s = i * 256 + wave * 64 + lane;
        int row = s >> 5, kq = s & 31;
        GLD16(&X[(long long)(m0 + row) * CDIM + kq * 8], &Asl[(i * 256 + wave * 64) * 8]);
    }

    floatx4 acc[2][8];
    bf16x4  kbf[2][8];

#pragma unroll
    for (int sel = 0; sel < 3; ++sel) {
        const __bf16* B = (sel == 0) ? Wq : (sel == 1) ? Wk : Wv;
#pragma unroll
        for (int i = 0; i < 2; ++i)
#pragma unroll
            for (int j = 0; j < 8; ++j)
                acc[i][j] = (floatx4){0.f, 0.f, 0.f, 0.f};

        for (int k0 = 0; k0 < CDIM; k0 += 64) {
            __syncthreads();
#pragma unroll
            for (int i = 0; i < 8; ++i) {
                int s = wave * 512 + i * 64 + lane;
                int row = s >> 3, kq = s & 7;
                GLD16(&B[(long long)row * CDIM + k0 + kq * 8], &Bsl[(wave * 512 + i * 64) * 8]);
            }
            __syncthreads();
#pragma unroll
            for (int ko = 0; ko < 2; ++ko) {
                bf16x8 af[2], bfr[8];
#pragma unroll
                for (int mt = 0; mt < 2; ++mt)
                    af[mt] = *(const bf16x8*)&Asl[(wm + mt * 16 + l15) * 256 + k0 + ko * 32 + quad * 8];
#pragma unroll
                for (int nt = 0; nt < 8; ++nt)
                    bfr[nt] = *(const bf16x8*)&Bsl[(wn + nt * 16 + l15) * 64 + ko * 32 + quad * 8];
#pragma unroll
                for (int mt = 0; mt < 2; ++mt)
#pragma unroll
                    for (int nt = 0; nt < 8; ++nt)
                        acc[mt][nt] = __builtin_amdgcn_mfma_f32_16x16x32_bf16(
                            bfr[nt], af[mt], acc[mt][nt], 0, 0, 0);
            }
        }

        if (sel == 0) {
#pragma unroll
            for (int mt = 0; mt < 2; ++mt) {
                int row = m0 + wm + mt * 16 + l15;
#pragma unroll
                for (int nt = 0; nt < 8; ++nt) {
                    int col0 = wn + nt * 16 + quad * 4;
                    float4 bb = *(const float4*)&bq[col0];
                    bf16x4 o;
#pragma unroll
                    for (int r = 0; r < 4; ++r) {
                        float v = acc[mt][nt][r] + ((r == 0) ? bb.x : (r == 1) ? bb.y : (r == 2) ? bb.z : bb.w);
                        v = v > 0.f ? v + 1.f : __expf(v);
                        o[r] = (__bf16)v;
                    }
                    *(bf16x4*)&Qo[(long long)row * CDIM + col0] = o;
                }
            }
        } else if (sel == 1) {
#pragma unroll
            for (int mt = 0; mt < 2; ++mt)
#pragma unroll
                for (int nt = 0; nt < 8; ++nt) {
                    int col0 = wn + nt * 16 + quad * 4;
                    float4 bb = *(const float4*)&bk[col0];
#pragma unroll
                    for (int r = 0; r < 4; ++r) {
                        float v = acc[mt][nt][r] + ((r == 0) ? bb.x : (r == 1) ? bb.y : (r == 2) ? bb.z : bb.w);
                        v = v > 0.f ? v + 1.f : __expf(v);
                        kbf[mt][nt][r] = (__bf16)v;
                    }
                }
        }
    }

    // ---- write K^T / V^T (swizzled) over the dead A/B LDS regions ----
    __syncthreads();
    {
        __bf16* KT = Bsl;
        __bf16* VT = Asl;
#pragma unroll
        for (int nt = 0; nt < 8; ++nt) {
            int col0 = wn + nt * 16 + quad * 4;
            float4 bb = *(const float4*)&bv[col0];
#pragma unroll
            for (int mt = 0; mt < 2; ++mt) {
                int row_t = wm + mt * 16 + l15;
#pragma unroll
                for (int r = 0; r < 4; ++r) {
                    KT[t_idx(col0 + r, row_t)] = kbf[mt][nt][r];
                    float vv = acc[mt][nt][r] + ((r == 0) ? bb.x : (r == 1) ? bb.y : (r == 2) ? bb.z : bb.w);
                    VT[t_idx(col0 + r, row_t)] = (__bf16)vv;
                }
            }
        }
    }
    __syncthreads();

    // ---- KS partial: column sums of feature-mapped K (staggered reads) ----
    {
        const __bf16* KT = Bsl;
        float s = 0.f;
#pragma unroll 8
        for (int i = 0; i < 64; ++i) {
            int ss = (i + tid) & 63;
            s += (float)KT[t_idx(tid, ss)];
        }
        pKS[(long long)blockIdx.x * 256 + tid] = s;
    }

    // ---- KV partial via MFMA: D[m][d] = sum_s V^T[m][s] * K[s][d] ----
    {
        const __bf16* KT = Bsl;
        const __bf16* VT = Asl;
        float* outKV = pKV + (long long)blockIdx.x * 8192;
#pragma unroll
        for (int hh = 0; hh < 2; ++hh) {
            int h = wave * 2 + hh;
            floatx4 kv[2][2];
#pragma unroll
            for (int mi = 0; mi < 2; ++mi)
#pragma unroll
                for (int di = 0; di < 2; ++di)
                    kv[mi][di] = (floatx4){0.f, 0.f, 0.f, 0.f};
#pragma unroll
            for (int ks = 0; ks < 2; ++ks) {
                bf16x8 a[2], b[2];
#pragma unroll
                for (int mi = 0; mi < 2; ++mi)
                    a[mi] = *(const bf16x8*)&VT[t_idx(h * 32 + mi * 16 + l15, ks * 32 + quad * 8)];
#pragma unroll
                for (int di = 0; di < 2; ++di)
                    b[di] = *(const bf16x8*)&KT[t_idx(h * 32 + di * 16 + l15, ks * 32 + quad * 8)];
#pragma unroll
                for (int mi = 0; mi < 2; ++mi)
#pragma unroll
                    for (int di = 0; di < 2; ++di)
                        kv[mi][di] = __builtin_amdgcn_mfma_f32_16x16x32_bf16(
                            a[mi], b[di], kv[mi][di], 0, 0, 0);
            }
#pragma unroll
            for (int mi = 0; mi < 2; ++mi)
#pragma unroll
                for (int di = 0; di < 2; ++di)
#pragma unroll
                    for (int r = 0; r < 4; ++r)
                        outKV[(long long)h * 1024 + (mi * 16 + quad * 4 + r) * 32 + di * 16 + l15]
                            = kv[mi][di][r];
        }
    }
}

// ---------------------------------------------------------------------------
// Reduce per-block partial KV/KS -> KVb/KSb.
// ---------------------------------------------------------------------------
__global__ __launch_bounds__(256)
void kv_reduce(const float* __restrict__ pKV, const float* __restrict__ pKS,
               float* __restrict__ KV, float* __restrict__ KS)
{
    __shared__ float red[256];
    const int bid = blockIdx.x, tid = threadIdx.x;
    if (bid < 256) {
        int o = bid * 128 + (tid & 127);      // 0..32767 : n*8192 + h*1024 + m*32 + d
        int half = tid >> 7;
        int n = o >> 13, r = o & 8191;
        const float* p = pKV + ((long long)n * 256 + half * 128) * 8192 + r;
        float s = 0.f;
#pragma unroll 8
        for (int b = 0; b < 128; ++b) s += p[(long long)b * 8192];
        red[tid] = s;
        __syncthreads();
        if (half == 0) KV[o] = red[tid] + red[tid + 128];
    } else {
        int n = bid - 256;
        const float* p = pKS + (long long)n * 256 * 256 + tid;
        float s = 0.f;
#pragma unroll 8
        for (int b = 0; b < 256; ++b) s += p[b * 256];
        KS[n * 256 + tid] = s;
    }
}

// ---------------------------------------------------------------------------
// W1 GEMM + ReLU: grid (MTOK/128, 2); n_base = blockIdx.y*256; O=512, K=256
// ---------------------------------------------------------------------------
__global__ __launch_bounds__(256, 2)
void gemm_relu(const __bf16* __restrict__ A, const __bf16* __restrict__ Bw,
               const float* __restrict__ bias, __bf16* __restrict__ C)
{
    __shared__ __bf16 Asl[128 * 64];
    __shared__ __bf16 Bsl[256 * 64];
    const int n_base = blockIdx.y * 256;
    const __bf16* B = Bw + (long long)n_base * CDIM;

    WIDE_PROLOGUE()
    for (int k0 = 0; k0 < CDIM; k0 += 64) {
        WIDE_STAGE(A, B, CDIM)
        WIDE_MFMA()
    }
#pragma unroll
    for (int mt = 0; mt < 4; ++mt) {
        int row = m0 + wm + mt * 16 + l15;
#pragma unroll
        for (int nt = 0; nt < 8; ++nt) {
            int col0 = wn + nt * 16 + quad * 4;
            float4 bb = *(const float4*)&bias[n_base + col0];
            bf16x4 o;
#pragma unroll
            for (int r = 0; r < 4; ++r) {
                float v = acc[mt][nt][r] + ((r == 0) ? bb.x : (r == 1) ? bb.y : (r == 2) ? bb.z : bb.w);
                o[r] = (__bf16)(v > 0.f ? v : 0.f);
            }
            *(bf16x4*)&C[(long long)row * FF + n_base + col0] = o;
        }
    }
}

// ---------------------------------------------------------------------------
// GEMM + residual + LayerNorm fused:  X = LN(X + A@B^T + bias) * g + be.
// WOUT: additionally writes the layer's fp32 [C, L] output from the
// normalized fp32 values (replaces the separate out_transpose kernel).
// Transpose bounce through Bsl as fp32 [256 c][stride 20] (20 KB), 8 chunks
// of 16 tokens. Write banks: quad*16 ^ l15 -> uniform 2-way (free).
// Read float4 banks: (20c+4j)&31 -> uniform 8/bank -> conflict-free.
// Global stores: 4 lanes per c-row, 64B-line coalesced.
// ---------------------------------------------------------------------------
template <int KDIM, bool WOUT>
__global__ __launch_bounds__(256, 2)
void gemm_ln(const __bf16* __restrict__ A, const __bf16* __restrict__ B,
             const float* __restrict__ bias, __bf16* X,
             const float* __restrict__ g, const float* __restrict__ be,
             float* __restrict__ out)
{
    __shared__ __bf16 Asl[128 * 64];
    __shared__ __bf16 Bsl[256 * 64];

    WIDE_PROLOGUE()
    for (int k0 = 0; k0 < KDIM; k0 += 64) {
        WIDE_STAGE(A, B, KDIM)
        WIDE_MFMA()
    }

    // bias + residual into fp32 acc
#pragma unroll
    for (int mt = 0; mt < 4; ++mt) {
        int row = m0 + wm + mt * 16 + l15;
#pragma unroll
        for (int nt = 0; nt < 8; ++nt) {
            int col0 = wn + nt * 16 + quad * 4;
            float4 bb = *(const float4*)&bias[col0];
            bf16x4 xr = *(const bf16x4*)&X[(long long)row * CDIM + col0];
            acc[mt][nt][0] += bb.x + (float)xr[0];
            acc[mt][nt][1] += bb.y + (float)xr[1];
            acc[mt][nt][2] += bb.z + (float)xr[2];
            acc[mt][nt][3] += bb.w + (float)xr[3];
        }
    }

    float psum[4], psq[4];
#pragma unroll
    for (int mt = 0; mt < 4; ++mt) {
        float s = 0.f, q = 0.f;
#pragma unroll
        for (int nt = 0; nt < 8; ++nt)
#pragma unroll
            for (int r = 0; r < 4; ++r) {
                float v = acc[mt][nt][r];
                s += v; q += v * v;
            }
        s += __shfl_xor(s, 16, 64); s += __shfl_xor(s, 32, 64);
        q += __shfl_xor(q, 16, 64); q += __shfl_xor(q, 32, 64);
        psum[mt] = s; psq[mt] = q;
    }

    float* red = (float*)Asl;           // red[row_local*4 + half*2 + {0,1}]
    const int half = wave >> 1;
    __syncthreads();
    if (quad == 0) {
#pragma unroll
        for (int mt = 0; mt < 4; ++mt) {
            int rl = wm + mt * 16 + l15;
            red[rl * 4 + half * 2 + 0] = psum[mt];
            red[rl * 4 + half * 2 + 1] = psq[mt];
        }
    }
    __syncthreads();

    // normalize in place (acc <- LN value), store X bf16
#pragma unroll
    for (int mt = 0; mt < 4; ++mt) {
        int rl  = wm + mt * 16 + l15;
        float tot = red[rl * 4 + 0] + red[rl * 4 + 2];
        float tsq = red[rl * 4 + 1] + red[rl * 4 + 3];
        float mean = tot * (1.f / 256.f);
        float var  = tsq * (1.f / 256.f) - mean * mean;
        float rstd = rsqrtf(var + 1e-5f);
        int row = m0 + rl;
#pragma unroll
        for (int nt = 0; nt < 8; ++nt) {
            int col0 = wn + nt * 16 + quad * 4;
            float4 gg = *(const float4*)&g[col0];
            float4 ee = *(const float4*)&be[col0];
            bf16x4 o;
#pragma unroll
            for (int r = 0; r < 4; ++r) {
                float gv = (r == 0) ? gg.x : (r == 1) ? gg.y : (r == 2) ? gg.z : gg.w;
                float ev = (r == 0) ? ee.x : (r == 1) ? ee.y : (r == 2) ? ee.z : ee.w;
                float v  = (acc[mt][nt][r] - mean) * rstd * gv + ev;
                acc[mt][nt][r] = v;
                o[r] = (__bf16)v;
            }
            *(bf16x4*)&X[(long long)row * CDIM + col0] = o;
        }
    }

    if constexpr (WOUT) {
        const int n  = m0 >> 14;              // LTOK = 16384
        const int l0 = m0 & (LTOK - 1);
        float* trans = (float*)Bsl;           // [256][stride 20] fp32 = 20 KB
        const int sub = lane >> 2, jj = lane & 3;
#pragma unroll
        for (int ch = 0; ch < 8; ++ch) {      // 16 token rows per chunk
            __syncthreads();
            if ((wave & 1) == (ch >> 2)) {    // rows ch*16..ch*16+15 owned here
                int mt = ch & 3;
#pragma unroll
                for (int nt = 0; nt < 8; ++nt) {
                    int col0 = wn + nt * 16 + quad * 4;
#pragma unroll
                    for (int r = 0; r < 4; ++r)
                        trans[(col0 + r) * 20 + l15] = acc[mt][nt][r];
                }
            }
            __syncthreads();
#pragma unroll
            for (int it = 0; it < 4; ++it) {
                int c = it * 64 + wave * 16 + sub;
                float4 v = *(const float4*)&trans[c * 20 + jj * 4];
                *(float4*)&out[(long long)n * CDIM * LTOK + (long long)c * LTOK
                               + l0 + ch * 16 + jj * 4] = v;
            }
        }
    }
}

// ---------------------------------------------------------------------------
// attn[n,l,h,m] = (Q·KV row m) / (Q·KS + eps); KV/KS rows in registers
// ---------------------------------------------------------------------------
__global__ __launch_bounds__(256)
void attn_kernel(const __bf16* __restrict__ Q, const float* __restrict__ KV,
                 const float* __restrict__ KS, __bf16* __restrict__ out)
{
    __shared__ float q_lds[16 * 256];
    const int n = blockIdx.y;
    const int tid = threadIdx.x;
    const int h = tid >> 5;
    const int m = tid & 31;

    float4 kvr[8], ksr[8];
    {
        const float4* kvp = (const float4*)&KV[(((long long)n * NH + h) * HD + m) * HD];
        const float4* ksp = (const float4*)&KS[((long long)n * NH + h) * HD];
#pragma unroll
        for (int i = 0; i < 8; ++i) { kvr[i] = kvp[i]; ksr[i] = ksp[i]; }
    }

    for (int it = 0; it < 4; ++it) {
        int l0 = blockIdx.x * 64 + it * 16;
        __syncthreads();
#pragma unroll
        for (int i = 0; i < 4; ++i) {
            int e = tid * 4 + i * 1024;
            int row = e >> 8, col = e & 255;
            bf16x4 q4 = *(const bf16x4*)&Q[(long long)(n * LTOK + l0 + row) * CDIM + col];
            float4 f;
            f.x = (float)q4[0]; f.y = (float)q4[1]; f.z = (float)q4[2]; f.w = (float)q4[3];
            *(float4*)&q_lds[e] = f;
        }
        __syncthreads();
#pragma unroll 2
        for (int t = 0; t < 16; ++t) {
            const float4* qr = (const float4*)&q_lds[t * 256 + h * 32];
            float num = 0.f, den = 0.f;
#pragma unroll
            for (int i = 0; i < 8; ++i) {
                float4 q4 = qr[i];
                num += q4.x * kvr[i].x + q4.y * kvr[i].y + q4.z * kvr[i].z + q4.w * kvr[i].w;
                den += q4.x * ksr[i].x + q4.y * ksr[i].y + q4.z * ksr[i].z + q4.w * ksr[i].w;
            }
            out[(long long)(n * LTOK + l0 + t) * CDIM + tid] = (__bf16)(num / (den + 1e-6f));
        }
    }
}

// ---------------------------------------------------------------------------
// Launch
// ---------------------------------------------------------------------------
extern "C" void kernel_launch(void* const* d_in, const int* in_sizes, int n_in,
                              void* d_out, int out_size, void* d_ws, size_t ws_size,
                              hipStream_t stream)
{
    const float* ref = (const float*)d_in[0];
    const float* Wq  = (const float*)d_in[1];  const float* bq = (const float*)d_in[2];
    const float* Wk  = (const float*)d_in[3];  const float* bk = (const float*)d_in[4];
    const float* Wv  = (const float*)d_in[5];  const float* bv = (const float*)d_in[6];
    const float* Wo  = (const float*)d_in[7];  const float* bo = (const float*)d_in[8];
    const float* g1  = (const float*)d_in[9];  const float* be1 = (const float*)d_in[10];
    const float* W1  = (const float*)d_in[11]; const float* c1 = (const float*)d_in[12];
    const float* W2  = (const float*)d_in[13]; const float* c2 = (const float*)d_in[14];
    const float* g2  = (const float*)d_in[15]; const float* be2 = (const float*)d_in[16];
    float* out = (float*)d_out;

    const size_t SZ = (size_t)MTOK * CDIM;
    __bf16* Xb = (__bf16*)d_ws;
    __bf16* Qb = Xb + SZ;
    __bf16* Kb = Qb + SZ;                    // layer loop: pKV partials, then attn out
    __bf16* Vb = Kb + SZ;                    // layer loop: pKS partials
    __bf16* Hb = Vb + SZ;                    // MTOK*FF
    float*  KVb = (float*)(Hb + 2 * SZ);
    float*  KSb = KVb + NB * NH * HD * HD;
    __bf16* Wqb = (__bf16*)(KSb + NB * NH * HD);
    const size_t WC = (size_t)NLAYER * CDIM * CDIM;
    const size_t WF = (size_t)NLAYER * FF * CDIM;
    __bf16* Wkb = Wqb + WC;
    __bf16* Wvb = Wkb + WC;
    __bf16* Wob = Wvb + WC;
    __bf16* W1b = Wob + WC;
    __bf16* W2b = W1b + WF;

    f2b_kernel<<<WC / 1024, 256, 0, stream>>>(Wq, Wqb);
    f2b_kernel<<<WC / 1024, 256, 0, stream>>>(Wk, Wkb);
    f2b_kernel<<<WC / 1024, 256, 0, stream>>>(Wv, Wvb);
    f2b_kernel<<<WC / 1024, 256, 0, stream>>>(Wo, Wob);
    f2b_kernel<<<WF / 1024, 256, 0, stream>>>(W1, W1b);
    f2b_kernel<<<WF / 1024, 256, 0, stream>>>(W2, W2b);

    dim3 tb(32, 8);
    patch_embed<<<dim3(HWDIM / 32, CDIM / 32, NB), tb, 0, stream>>>(ref, Xb);

    for (int l = 0; l < NLAYER; ++l) {
        const __bf16* Wq_l = Wqb + (size_t)l * CDIM * CDIM;
        const __bf16* Wk_l = Wkb + (size_t)l * CDIM * CDIM;
        const __bf16* Wv_l = Wvb + (size_t)l * CDIM * CDIM;
        const __bf16* Wo_l = Wob + (size_t)l * CDIM * CDIM;
        const __bf16* W1_l = W1b + (size_t)l * FF * CDIM;
        const __bf16* W2_l = W2b + (size_t)l * CDIM * FF;
        const float* bq_l = bq + (size_t)l * CDIM;
        const float* bk_l = bk + (size_t)l * CDIM;
        const float* bv_l = bv + (size_t)l * CDIM;
        const float* bo_l = bo + (size_t)l * CDIM;
        const float* c1_l = c1 + (size_t)l * FF;
        const float* c2_l = c2 + (size_t)l * CDIM;
        const float* g1_l = g1 + (size_t)l * CDIM;
        const float* g2_l = g2 + (size_t)l * CDIM;
        const float* be1_l = be1 + (size_t)l * CDIM;
        const float* be2_l = be2 + (size_t)l * CDIM;

        // fused QKV + partial KV/KS (X read once; K,V never hit global)
        qkv_kv<<<MTOK / 64, 256, 0, stream>>>(
            Xb, Wq_l, Wk_l, Wv_l, bq_l, bk_l, bv_l,
            Qb, (float*)Kb, (float*)Vb);

        kv_reduce<<<260, 256, 0, stream>>>((const float*)Kb, (const float*)Vb, KVb, KSb);

        attn_kernel<<<dim3(LTOK / 64, NB), 256, 0, stream>>>(Qb, KVb, KSb, Kb);

        // X = LN(X + attn@Wo^T + bo)
        gemm_ln<CDIM, false><<<MTOK / 128, 256, 0, stream>>>(
            Kb, Wo_l, bo_l, Xb, g1_l, be1_l, nullptr);

        // H = relu(X@W1^T + c1)
        gemm_relu<<<dim3(MTOK / 128, 2), 256, 0, stream>>>(Xb, W1_l, c1_l, Hb);

        // X = LN(X + H@W2^T + c2), + fp32 [C,L] layer output (fused transpose)
        gemm_ln<FF, true><<<MTOK / 128, 256, 0, stream>>>(
            Hb, W2_l, c2_l, Xb, g2_l, be2_l,
            out + (size_t)l * NB * CDIM * LTOK);
    }
}